// Round 11
// baseline (157.320 us; speedup 1.0000x reference)
//
#include <hip/hip_runtime.h>

#define NSEQ 2048
#define DIM  512
#define NKT  64                    // kv tiles of 32
#define TILEB 32768                // 32*512*2 bytes
#define VOFF  65536                // V dbuf after K dbuf
#define POFF  131072               // P: par*4096 + u*2048 + grp*1024
#define FOFF  139264               // f: par*256 + u*128 + grp*64
#define SMEMB 139776
#define SMEMB4 (4 * TILEB + 4096)  // fallback layout

typedef __bf16 bf16x8 __attribute__((ext_vector_type(8)));
typedef float  f32x4  __attribute__((ext_vector_type(4)));

__device__ __forceinline__ void gld16(const void* g, void* l) {
  __builtin_amdgcn_global_load_lds(
      (const __attribute__((address_space(1))) unsigned int*)g,
      (__attribute__((address_space(3))) unsigned int*)l, 16, 0, 0);
}

#define MFMA __builtin_amdgcn_mfma_f32_16x16x32_bf16

// ---------- pre-pass: K -> bf16, per-tile [32 kv][512 d], byte ^= ((row&7)<<4)
__global__ __launch_bounds__(256) void prep_k(const float* __restrict__ ks,
                                              char* __restrict__ kp) {
  int b = blockIdx.x >> 6, kt = blockIdx.x & 63;
  int t = threadIdx.x;
  const float* src = ks + ((size_t)(b * NSEQ + kt * 32)) * DIM;
  char* dst = kp + ((size_t)(b * 64 + kt)) * TILEB;
#pragma unroll
  for (int i = 0; i < 8; ++i) {
    int c = t + i * 256;
    int row = c >> 6;
    int d0 = (c & 63) * 8;
    const float4* s4 = (const float4*)(src + row * DIM + d0);
    float4 x = s4[0], y = s4[1];
    bf16x8 h;
    h[0] = (__bf16)x.x; h[1] = (__bf16)x.y; h[2] = (__bf16)x.z; h[3] = (__bf16)x.w;
    h[4] = (__bf16)y.x; h[5] = (__bf16)y.y; h[6] = (__bf16)y.z; h[7] = (__bf16)y.w;
    *(bf16x8*)(dst + row * 1024 + ((d0 * 2) ^ ((row & 7) << 4))) = h;
  }
}

// ---------- pre-pass: V -> bf16 transposed per tile (verified layout)
__global__ __launch_bounds__(256) void prep_v(const float* __restrict__ vs,
                                              char* __restrict__ vtp) {
  __shared__ __align__(16) char lds[TILEB];
  int b = blockIdx.x >> 6, kt = blockIdx.x & 63;
  int t = threadIdx.x;
  const float* src = vs + ((size_t)(b * NSEQ + kt * 32)) * DIM;
#pragma unroll
  for (int i = 0; i < 8; ++i) {
    int c = t + i * 256;
    int kv = c >> 6;
    int d0 = (c & 63) * 8;
    const float4* s4 = (const float4*)(src + kv * DIM + d0);
    float4 x = s4[0], y = s4[1];
    float vals[8] = {x.x, x.y, x.z, x.w, y.x, y.y, y.z, y.w};
#pragma unroll
    for (int jj = 0; jj < 8; ++jj) {
      int d = d0 + jj;
      int byte = (d >> 1) * 128 + (((((d & 1) * 64) + kv * 2)) ^ (((d >> 1) & 7) << 4));
      *(__bf16*)(lds + byte) = (__bf16)vals[jj];
    }
  }
  __syncthreads();
  char* dst = vtp + ((size_t)(b * 64 + kt)) * TILEB;
#pragma unroll
  for (int i = 0; i < 8; ++i) {
    int c16 = t + i * 256;
    *(bf16x8*)(dst + c16 * 16) = *(const bf16x8*)(lds + c16 * 16);
  }
}

// ---------- producer/consumer kernel: 6 waves = 2 units x (1 prod + 2 cons)
__global__ __launch_bounds__(384, 1) void attn_pc(
    const float* __restrict__ qs, const char* __restrict__ kp,
    const char* __restrict__ vtp, const float* __restrict__ scale,
    float* __restrict__ out) {
  extern __shared__ __align__(16) char smem[];
  int b  = blockIdx.x & 7;           // batch -> XCD
  int qt = blockIdx.x >> 3;          // 0..31
  int tid = threadIdx.x;
  int w = tid >> 6, lane = tid & 63;
  int c = lane & 15, g = lane >> 4;
  const bool prod = (w < 2);
  const int u = prod ? w : ((w - 2) >> 1);   // unit 0/1
  const int j = (w - 2) & 1;                 // consumer d-half
  const int q0 = qt * 64 + u * 32;

  const char* kpb = kp  + (size_t)b * 64 * TILEB;
  const char* vpb = vtp + (size_t)b * 64 * TILEB;

  const int csw = (c & 7) << 4;
  const int vt_lane = (c >> 1) * 128 +
      (((((c & 1) * 64) + g * 16)) ^ (((c >> 1) & 7) << 4));
  const int qb = (c >> 1) * 128;
  const int qh = (c & 1) * 64;
  const int qx = ((c >> 1) & 7) << 4;

  float cc = 1.4426950408889634f / scale[0];   // log2(e)/scale folded into Q

  // shared register file: producer = Q frags (bitcast bf16x8), consumer = acc
  f32x4 st[32];
  float mrowA = -1e30f, mrowB = -1e30f;        // producer-only state

  if (prod) {
#pragma unroll
    for (int k = 0; k < 16; ++k) {
      int d = k * 32 + g * 8;
#pragma unroll
      for (int grp = 0; grp < 2; ++grp) {
        int row = q0 + grp * 16 + c;
        const float4* p = (const float4*)(qs + ((size_t)(b * NSEQ + row)) * DIM + d);
        float4 x = p[0], y = p[1];
        float vals[8] = {x.x, x.y, x.z, x.w, y.x, y.y, y.z, y.w};
        bf16x8 h;
#pragma unroll
        for (int jj = 0; jj < 8; ++jj) {
          float mlt = (d + jj == 0) ? cc : -cc;   // Minkowski sign fold
          h[jj] = (__bf16)(vals[jj] * mlt);
        }
        st[grp * 16 + k] = __builtin_bit_cast(f32x4, h);
      }
    }
  } else {
#pragma unroll
    for (int i = 0; i < 32; ++i) st[i] = (f32x4){0.f, 0.f, 0.f, 0.f};
  }

  // cooperative tile staging: 384 threads x 16B, 6 rounds (last partial)
  auto STAGE = [&](const char* src, char* dst) {
#pragma unroll
    for (int i = 0; i < 6; ++i) {
      int o = tid * 16 + i * 6144;
      if (o < TILEB) gld16(src + o, dst + o);
    }
  };

  // producer: QK(tile) -> softmax -> P/f into parity buffers
  auto PRODUCE = [&](int tile, int par, bool first) {
    f32x4 a0A={0,0,0,0}, a1A={0,0,0,0}, b0A={0,0,0,0}, b1A={0,0,0,0};
    f32x4 a0B={0,0,0,0}, a1B={0,0,0,0}, b0B={0,0,0,0}, b1B={0,0,0,0};
    const char* krl = smem + (tile & 1) * TILEB + c * 1024;
    const char* krh = krl + 16 * 1024;
#pragma unroll
    for (int k = 0; k < 16; ++k) {
      int bir = (k * 64 + g * 16) ^ csw;
      bf16x8 kfl = *(const bf16x8*)(krl + bir);
      bf16x8 kfh = *(const bf16x8*)(krh + bir);
      bf16x8 qA = __builtin_bit_cast(bf16x8, st[k]);
      bf16x8 qB = __builtin_bit_cast(bf16x8, st[16 + k]);
      if (k & 1) {
        b0A = MFMA(kfl, qA, b0A, 0,0,0); b1A = MFMA(kfh, qA, b1A, 0,0,0);
        b0B = MFMA(kfl, qB, b0B, 0,0,0); b1B = MFMA(kfh, qB, b1B, 0,0,0);
      } else {
        a0A = MFMA(kfl, qA, a0A, 0,0,0); a1A = MFMA(kfh, qA, a1A, 0,0,0);
        a0B = MFMA(kfl, qB, a0B, 0,0,0); a1B = MFMA(kfh, qB, a1B, 0,0,0);
      }
    }
    f32x4 slA = a0A + b0A, shA = a1A + b1A;
    f32x4 slB = a0B + b0B, shB = a1B + b1B;
    float mmA = fmaxf(fmaxf(fmaxf(slA[0], slA[1]), fmaxf(slA[2], slA[3])),
                      fmaxf(fmaxf(shA[0], shA[1]), fmaxf(shA[2], shA[3])));
    float mmB = fmaxf(fmaxf(fmaxf(slB[0], slB[1]), fmaxf(slB[2], slB[3])),
                      fmaxf(fmaxf(shB[0], shB[1]), fmaxf(shB[2], shB[3])));
    mmA = fmaxf(mmA, __shfl_xor(mmA, 16)); mmA = fmaxf(mmA, __shfl_xor(mmA, 32));
    mmB = fmaxf(mmB, __shfl_xor(mmB, 16)); mmB = fmaxf(mmB, __shfl_xor(mmB, 32));
    float fA = 1.0f, fB = 1.0f;
    if (first) {
      mrowA = mmA; mrowB = mmB;
    } else if (__any((mmA > mrowA + 11.0f) || (mmB > mrowB + 11.0f))) {
      float MA = fmaxf(mrowA, mmA), MB = fmaxf(mrowB, mmB);
      fA = exp2f(mrowA - MA); fB = exp2f(mrowB - MB);
      mrowA = MA; mrowB = MB;
    }
    char* fb = smem + FOFF + par * 256 + u * 128;
    if (g == 0) {                                // lane c holds q=c
      *(float*)(fb + c * 4)      = fA;
      *(float*)(fb + 64 + c * 4) = fB;
    }
    char* pbA = smem + POFF + par * 4096 + u * 2048;
    char* pbB = pbA + 1024;
#pragma unroll
    for (int r = 0; r < 4; ++r) {
      int kvl = 4 * g + r;
      float pAl = exp2f(slA[r] - mrowA), pAh = exp2f(shA[r] - mrowA);
      float pBl = exp2f(slB[r] - mrowB), pBh = exp2f(shB[r] - mrowB);
      *(__bf16*)(pbA + qb + ((qh + kvl * 2) ^ qx))        = (__bf16)pAl;
      *(__bf16*)(pbA + qb + ((qh + (16 + kvl) * 2) ^ qx)) = (__bf16)pAh;
      *(__bf16*)(pbB + qb + ((qh + kvl * 2) ^ qx))        = (__bf16)pBl;
      *(__bf16*)(pbB + qb + ((qh + (16 + kvl) * 2) ^ qx)) = (__bf16)pBh;
    }
  };

  // consumer: rescale + PV(t) on own d-half
  auto CONSUME = [&](int t) {
    int par = t & 1;
    const char* fb = smem + FOFF + par * 256 + u * 128;
    float fvA = *(const float*)(fb + c * 4);
    float fvB = *(const float*)(fb + 64 + c * 4);
    if (__any((fvA < 1.0f) || (fvB < 1.0f))) {
      float fA0 = __shfl(fvA, 4*g+0), fA1 = __shfl(fvA, 4*g+1);
      float fA2 = __shfl(fvA, 4*g+2), fA3 = __shfl(fvA, 4*g+3);
      float fB0 = __shfl(fvB, 4*g+0), fB1 = __shfl(fvB, 4*g+1);
      float fB2 = __shfl(fvB, 4*g+2), fB3 = __shfl(fvB, 4*g+3);
#pragma unroll
      for (int i = 0; i < 16; ++i) {
        st[i][0] *= fA0; st[i][1] *= fA1; st[i][2] *= fA2; st[i][3] *= fA3;
        st[16+i][0] *= fB0; st[16+i][1] *= fB1; st[16+i][2] *= fB2; st[16+i][3] *= fB3;
      }
    }
    const char* pbA = smem + POFF + par * 4096 + u * 2048;
    bf16x8 pfA = *(const bf16x8*)(pbA + vt_lane);
    bf16x8 pfB = *(const bf16x8*)(pbA + 1024 + vt_lane);
    const char* vr = smem + VOFF + par * TILEB + j * 16384 + vt_lane;
#pragma unroll
    for (int dtl = 0; dtl < 16; ++dtl) {
      bf16x8 vf = *(const bf16x8*)(vr + dtl * 1024);    // read once, used twice
      st[dtl]      = MFMA(pfA, vf, st[dtl], 0, 0, 0);
      st[16 + dtl] = MFMA(pfB, vf, st[16 + dtl], 0, 0, 0);
    }
  };

  // prologue: K(0), K(1), V(0)
  STAGE(kpb, smem);
  STAGE(kpb + TILEB, smem + TILEB);
  STAGE(vpb, smem + VOFF);
  __syncthreads();
  if (prod) PRODUCE(0, 0, true);
  __syncthreads();

  // main loop: stage K(t+2),V(t+1) || producer S(t+1) || consumer PV(t)
  for (int t = 0; t < NKT; ++t) {
    if (t + 2 < NKT) STAGE(kpb + (size_t)(t + 2) * TILEB, smem + (t & 1) * TILEB);
    if (t + 1 < NKT) STAGE(vpb + (size_t)(t + 1) * TILEB, smem + VOFF + ((t + 1) & 1) * TILEB);
    if (prod) {
      if (t + 1 < NKT) PRODUCE(t + 1, (t + 1) & 1, false);
    } else {
      CONSUME(t);
    }
    __syncthreads();
  }

  // epilogue: merge d-halves (pbuf area dead -> merge scratch)
  char* mrg = smem + POFF + u * 512;
  float ssA[4], ssB[4];
  if (!prod) {
#pragma unroll
    for (int r = 0; r < 4; ++r) {
      float sA = 0.f, sB = 0.f;
#pragma unroll
      for (int i = 0; i < 16; ++i) {
        sA += st[i][r] * st[i][r];
        sB += st[16 + i][r] * st[16 + i][r];
      }
      sA += __shfl_xor(sA, 1); sA += __shfl_xor(sA, 2);
      sA += __shfl_xor(sA, 4); sA += __shfl_xor(sA, 8);
      sB += __shfl_xor(sB, 1); sB += __shfl_xor(sB, 2);
      sB += __shfl_xor(sB, 4); sB += __shfl_xor(sB, 8);
      ssA[r] = sA; ssB[r] = sB;
    }
    if (j == 1 && c == 0) {
#pragma unroll
      for (int r = 0; r < 4; ++r) {
        *(float*)(mrg + (4 * g + r) * 4)      = ssA[r];
        *(float*)(mrg + 64 + (4 * g + r) * 4) = ssB[r];
      }
    }
  }
  __syncthreads();
  if (!prod && j == 0) {
#pragma unroll
    for (int grp = 0; grp < 2; ++grp) {
#pragma unroll
      for (int r = 0; r < 4; ++r) {
        float sown = grp ? ssB[r] : ssA[r];
        float soth = *(const float*)(mrg + grp * 64 + (4 * g + r) * 4);
        float ss = sown + soth;
        f32x4 acc0 = grp ? st[16] : st[0];
        float a0 = __shfl(acc0[r], lane & 48);       // c==0 lane holds O[q][0]
        float d2 = fabsf(2.f * a0 * a0 - ss);
        float inv = rsqrtf(fmaxf(d2, 1e-8f));
        if (c == 0) *(float*)(mrg + 128 + grp * 64 + (4 * g + r) * 4) = inv;
        float* orow = out + ((size_t)(b * NSEQ + q0 + grp * 16 + 4 * g + r)) * DIM + c;
#pragma unroll
        for (int i = 0; i < 16; ++i)
          orow[i * 16] = (grp ? st[16 + i][r] : st[i][r]) * inv;
      }
    }
  }
  __syncthreads();
  if (!prod && j == 1) {
#pragma unroll
    for (int grp = 0; grp < 2; ++grp) {
#pragma unroll
      for (int r = 0; r < 4; ++r) {
        float inv = *(const float*)(mrg + 128 + grp * 64 + (4 * g + r) * 4);
        float* orow = out + ((size_t)(b * NSEQ + q0 + grp * 16 + 4 * g + r)) * DIM + 256 + c;
#pragma unroll
        for (int i = 0; i < 16; ++i)
          orow[i * 16] = (grp ? st[16 + i][r] : st[i][r]) * inv;
      }
    }
  }
}

// ---------- fallback: R5-proven 4-wave 16q kernel (152 us)
__global__ __launch_bounds__(256) void attn_main4(
    const float* __restrict__ qs, const char* __restrict__ kp,
    const char* __restrict__ vtp, const float* __restrict__ scale,
    float* __restrict__ out) {
  extern __shared__ __align__(16) char smem[];
  int b  = blockIdx.x & 7;
  int qt = blockIdx.x >> 3;
  int tid = threadIdx.x;
  int w = tid >> 6, lane = tid & 63;
  int c = lane & 15, g = lane >> 4;
  int q0 = qt * 64 + w * 16;

  char* kbuf = smem;
  char* vbuf = smem + 2 * TILEB;
  char* plds = smem + 4 * TILEB + w * 1024;

  float cc = 1.4426950408889634f / scale[0];

  bf16x8 qf[16];
#pragma unroll
  for (int k = 0; k < 16; ++k) {
    int d = k * 32 + g * 8;
    const float4* p = (const float4*)(qs + ((size_t)(b * NSEQ + q0 + c)) * DIM + d);
    float4 x = p[0], y = p[1];
    float vals[8] = {x.x, x.y, x.z, x.w, y.x, y.y, y.z, y.w};
    bf16x8 h;
#pragma unroll
    for (int jj = 0; jj < 8; ++jj) {
      float mlt = (d + jj == 0) ? cc : -cc;
      h[jj] = (__bf16)(vals[jj] * mlt);
    }
    qf[k] = h;
  }

  f32x4 acc[32];
#pragma unroll
  for (int i = 0; i < 32; ++i) acc[i] = (f32x4){0.f, 0.f, 0.f, 0.f};
  float mrow = -1e30f;

  const char* kpb = kp  + (size_t)b * 64 * TILEB;
  const char* vpb = vtp + (size_t)b * 64 * TILEB;

  const int csw = (c & 7) << 4;
  const int vt_lane = (c >> 1) * 128 +
      (((((c & 1) * 64) + g * 16)) ^ (((c >> 1) & 7) << 4));
  const int qb = (c >> 1) * 128;
  const int qh = (c & 1) * 64;
  const int qx = ((c >> 1) & 7) << 4;

#pragma unroll
  for (int i = 0; i < 8; ++i) {
    int o = tid * 16 + i * 4096;
    gld16(kpb + o, kbuf + o);
    gld16(vpb + o, vbuf + o);
    gld16(kpb + TILEB + o, kbuf + TILEB + o);
  }
  __syncthreads();

  f32x4 sl, sh;
  bf16x8 pf;
  {
    f32x4 sa0 = {0,0,0,0}, sb0 = {0,0,0,0}, sa1 = {0,0,0,0}, sb1 = {0,0,0,0};
    const char* krl = kbuf + c * 1024;
    const char* krh = krl + 16 * 1024;
#pragma unroll
    for (int k = 0; k < 16; ++k) {
      int bir = (k * 64 + g * 16) ^ csw;
      bf16x8 kfl = *(const bf16x8*)(krl + bir);
      bf16x8 kfh = *(const bf16x8*)(krh + bir);
      if (k & 1) { sb0 = MFMA(kfl, qf[k], sb0, 0,0,0); sb1 = MFMA(kfh, qf[k], sb1, 0,0,0); }
      else       { sa0 = MFMA(kfl, qf[k], sa0, 0,0,0); sa1 = MFMA(kfh, qf[k], sa1, 0,0,0); }
    }
    sl = sa0 + sb0; sh = sa1 + sb1;
    float mm = fmaxf(fmaxf(fmaxf(sl[0], sl[1]), fmaxf(sl[2], sl[3])),
                     fmaxf(fmaxf(sh[0], sh[1]), fmaxf(sh[2], sh[3])));
    mm = fmaxf(mm, __shfl_xor(mm, 16));
    mm = fmaxf(mm, __shfl_xor(mm, 32));
    mrow = mm;
#pragma unroll
    for (int r = 0; r < 4; ++r) {
      float pvl = exp2f(sl[r] - mrow);
      float pvh = exp2f(sh[r] - mrow);
      int kvl = 4 * g + r;
      *(__bf16*)(plds + qb + ((qh + kvl * 2) ^ qx))        = (__bf16)pvl;
      *(__bf16*)(plds + qb + ((qh + (16 + kvl) * 2) ^ qx)) = (__bf16)pvh;
    }
    pf = *(const bf16x8*)(plds + vt_lane);
  }
  __syncthreads();

  for (int t = 0; t < NKT - 1; ++t) {
    if (t + 2 < NKT) {
      const char* ksrc = kpb + (size_t)(t + 2) * TILEB;
      char* kdst = kbuf + (t & 1) * TILEB;
#pragma unroll
      for (int i = 0; i < 8; ++i) {
        int o = tid * 16 + i * 4096;
        gld16(ksrc + o, kdst + o);
      }
    }
    {
      const char* vsrc = vpb + (size_t)(t + 1) * TILEB;
      char* vdst = vbuf + ((t + 1) & 1) * TILEB;
#pragma unroll
      for (int i = 0; i < 8; ++i) {
        int o = tid * 16 + i * 4096;
        gld16(vsrc + o, vdst + o);
      }
    }
    f32x4 sa0 = {0,0,0,0}, sb0 = {0,0,0,0}, sa1 = {0,0,0,0}, sb1 = {0,0,0,0};
    const char* krl = kbuf + ((t + 1) & 1) * TILEB + c * 1024;
    const char* krh = krl + 16 * 1024;
    const char* vr  = vbuf + (t & 1) * TILEB + vt_lane;
#pragma unroll
    for (int k = 0; k < 16; ++k) {
      int bir = (k * 64 + g * 16) ^ csw;
      bf16x8 kfl = *(const bf16x8*)(krl + bir);
      bf16x8 kfh = *(const bf16x8*)(krh + bir);
      bf16x8 vf0 = *(const bf16x8*)(vr + (2 * k) * 1024);
      bf16x8 vf1 = *(const bf16x8*)(vr + (2 * k + 1) * 1024);
      if (k & 1) { sb0 = MFMA(kfl, qf[k], sb0, 0,0,0); sb1 = MFMA(kfh, qf[k], sb1, 0,0,0); }
      else       { sa0 = MFMA(kfl, qf[k], sa0, 0,0,0); sa1 = MFMA(kfh, qf[k], sa1, 0,0,0); }
      acc[2 * k]     = MFMA(pf, vf0, acc[2 * k], 0, 0, 0);
      acc[2 * k + 1] = MFMA(pf, vf1, acc[2 * k + 1], 0, 0, 0);
    }
    sl = sa0 + sb0; sh = sa1 + sb1;

    float mm = fmaxf(fmaxf(fmaxf(sl[0], sl[1]), fmaxf(sl[2], sl[3])),
                     fmaxf(fmaxf(sh[0], sh[1]), fmaxf(sh[2], sh[3])));
    mm = fmaxf(mm, __shfl_xor(mm, 16));
    mm = fmaxf(mm, __shfl_xor(mm, 32));
    if (__any(mm > mrow + 11.0f)) {
      float mn = fmaxf(mrow, mm);
      float f = exp2f(mrow - mn);
      mrow = mn;
      float f0 = __shfl(f, 4 * g + 0), f1 = __shfl(f, 4 * g + 1);
      float f2 = __shfl(f, 4 * g + 2), f3 = __shfl(f, 4 * g + 3);
#pragma unroll
      for (int i = 0; i < 32; ++i) {
        acc[i][0] *= f0; acc[i][1] *= f1; acc[i][2] *= f2; acc[i][3] *= f3;
      }
    }
#pragma unroll
    for (int r = 0; r < 4; ++r) {
      float pvl = exp2f(sl[r] - mrow);
      float pvh = exp2f(sh[r] - mrow);
      int kvl = 4 * g + r;
      *(__bf16*)(plds + qb + ((qh + kvl * 2) ^ qx))        = (__bf16)pvl;
      *(__bf16*)(plds + qb + ((qh + (16 + kvl) * 2) ^ qx)) = (__bf16)pvh;
    }
    pf = *(const bf16x8*)(plds + vt_lane);
    __syncthreads();
  }
  {
    const char* vr = vbuf + ((NKT - 1) & 1) * TILEB + vt_lane;
#pragma unroll
    for (int dtl = 0; dtl < 32; ++dtl) {
      bf16x8 vf = *(const bf16x8*)(vr + dtl * 1024);
      acc[dtl] = MFMA(pf, vf, acc[dtl], 0, 0, 0);
    }
  }
#pragma unroll
  for (int r = 0; r < 4; ++r) {
    float ss = 0.f;
#pragma unroll
    for (int dtl = 0; dtl < 32; ++dtl) ss += acc[dtl][r] * acc[dtl][r];
    ss += __shfl_xor(ss, 1);
    ss += __shfl_xor(ss, 2);
    ss += __shfl_xor(ss, 4);
    ss += __shfl_xor(ss, 8);
    float a0 = __shfl(acc[0][r], lane & 48);
    float d2 = fabsf(2.f * a0 * a0 - ss);
    float inv = rsqrtf(fmaxf(d2, 1e-8f));
    float* orow = out + ((size_t)(b * NSEQ + q0 + 4 * g + r)) * DIM + c;
#pragma unroll
    for (int dtl = 0; dtl < 32; ++dtl) orow[dtl * 16] = acc[dtl][r] * inv;
  }
}

extern "C" void kernel_launch(void* const* d_in, const int* in_sizes, int n_in,
                              void* d_out, int out_size, void* d_ws, size_t ws_size,
                              hipStream_t stream) {
  (void)in_sizes; (void)n_in; (void)out_size;
  const float* qs = (const float*)d_in[0];
  const float* ks = (const float*)d_in[1];
  const float* vs = (const float*)d_in[2];
  const float* scale = (const float*)d_in[3];
  // d_in[4] (bias) uniform across softmax axis -> invariant -> unused
  float* out = (float*)d_out;

  size_t need = (size_t)2 * 8 * 64 * TILEB;
  if (ws_size < need) return;
  char* kp  = (char*)d_ws;
  char* vtp = (char*)d_ws + (size_t)8 * 64 * TILEB;

  prep_k<<<512, 256, 0, stream>>>(ks, kp);
  prep_v<<<512, 256, 0, stream>>>(vs, vtp);

  hipFuncAttributes a;
  bool usePC = false;
  if (hipFuncGetAttributes(&a, (const void*)attn_pc) == hipSuccess)
    usePC = (a.localSizeBytes == 0 && a.numRegs >= 100);

  if (usePC) {
    hipFuncSetAttribute((const void*)attn_pc,
                        hipFuncAttributeMaxDynamicSharedMemorySize, SMEMB);
    attn_pc<<<256, 384, SMEMB, stream>>>(qs, kp, vtp, scale, out);
  } else {
    hipFuncSetAttribute((const void*)attn_main4,
                        hipFuncAttributeMaxDynamicSharedMemorySize, SMEMB4);
    attn_main4<<<256, 256, SMEMB4, stream>>>(qs, kp, vtp, scale, out);
  }
}